// Round 9
// baseline (311.035 us; speedup 1.0000x reference)
//
#include <hip/hip_runtime.h>
#include <hip/hip_bf16.h>

#define N_GRAPHS 64

// ---------------------------------------------------------------------------
__global__ void k_deg(const int* __restrict__ dst, int E, int* __restrict__ deg) {
    int i = blockIdx.x * blockDim.x + threadIdx.x;
    if (i < E) atomicAdd(&deg[dst[i]], 1);
}

// dis/xp + per-block deg sums (fused)
__global__ void k_dis_bsum(const int* __restrict__ deg, const float* __restrict__ x,
                           float* __restrict__ dis, float* __restrict__ xp,
                           int* __restrict__ bsum, int N) {
    int i = blockIdx.x * 256 + threadIdx.x;
    int dv = (i < N) ? deg[i] : 0;
    if (i < N) {
        float d = rsqrtf((float)(dv + 1));
        dis[i] = d;
        xp[i]  = d * x[i];
    }
    int v = dv;
#pragma unroll
    for (int o = 1; o < 64; o <<= 1) v += __shfl_xor(v, o);
    __shared__ int ws4[4];
    if ((threadIdx.x & 63) == 0) ws4[threadIdx.x >> 6] = v;
    __syncthreads();
    if (threadIdx.x == 0) bsum[blockIdx.x] = ws4[0] + ws4[1] + ws4[2] + ws4[3];
}

__device__ inline int block_scan_inc(int v, int* wsum) {
    int lane = threadIdx.x & 63, w = threadIdx.x >> 6;
    int iv = v;
#pragma unroll
    for (int o = 1; o < 64; o <<= 1) {
        int t = __shfl_up(iv, o);
        if (lane >= o) iv += t;
    }
    if (lane == 63) wsum[w] = iv;
    __syncthreads();
    int add = 0;
    for (int k = 0; k < w; ++k) add += wsum[k];
    return iv + add;
}

__global__ void k_scan_sums(const int* __restrict__ bsum, int nb, int* __restrict__ boff) {
    __shared__ int wsum[4];
    int tid = threadIdx.x;
    int v = (tid < nb) ? bsum[tid] : 0;
    int inc = block_scan_inc(v, wsum);
    if (tid < nb) boff[tid] = inc - v;   // exclusive
}

__global__ void k_scan_apply(const int* __restrict__ deg, const int* __restrict__ boff,
                             int* __restrict__ row_ptr, int N) {
    __shared__ int wsum[4];
    int b = blockIdx.x, i = b * 256 + threadIdx.x;
    int v = (i < N) ? deg[i] : 0;
    int inc = block_scan_inc(v, wsum) + boff[b];
    if (i < N) {
        row_ptr[i] = inc - v;
        if (i == N - 1) row_ptr[N] = inc;
    }
}

__global__ void k_scatter(const int* __restrict__ src, const int* __restrict__ dst, int E,
                          const int* __restrict__ row_ptr, int* __restrict__ fill,
                          int* __restrict__ csr_src) {
    int e = blockIdx.x * blockDim.x + threadIdx.x;
    if (e < E) {
        int d = dst[e];
        int pos = row_ptr[d] + atomicAdd(&fill[d], 1);
        csr_src[pos] = src[e];
    }
}

// td2[d] = ( dis[d] * (sum xp[s] + xp[d]),  dis[d] )
__global__ void k_agg_scalar(const float* __restrict__ xp, const float* __restrict__ dis,
                             const int* __restrict__ row_ptr, const int* __restrict__ csr,
                             float2* __restrict__ td2, int N) {
    int d = blockIdx.x * blockDim.x + threadIdx.x;
    if (d >= N) return;
    float acc = xp[d];
    int e0 = row_ptr[d], e1 = row_ptr[d + 1];
    int e = e0;
    for (; e + 8 <= e1; e += 8) {
        int s0 = csr[e],     s1 = csr[e + 1], s2 = csr[e + 2], s3 = csr[e + 3];
        int s4 = csr[e + 4], s5 = csr[e + 5], s6 = csr[e + 6], s7 = csr[e + 7];
        acc += ((xp[s0] + xp[s1]) + (xp[s2] + xp[s3]))
             + ((xp[s4] + xp[s5]) + (xp[s6] + xp[s7]));
    }
    for (; e < e1; ++e) acc += xp[csr[e]];
    float dd = dis[d];
    td2[d] = make_float2(dd * acc, dd);
}

// ---------------------------------------------------------------------------
// Layer-2 aggregation with rank-1 h1 recompute (LDS-free, high occupancy)
__global__ void k_h1agg(const float2* __restrict__ td2,
                        const float4* __restrict__ W1f4, const float4* __restrict__ b1f4,
                        const int* __restrict__ row_ptr, const int* __restrict__ csr,
                        float4* __restrict__ out4, int N) {
    int node = blockIdx.x * 8 + (threadIdx.x >> 5);
    int lane = threadIdx.x & 31;
    if (node >= N) return;
    const float4 w1 = W1f4[lane];
    const float4 bv = b1f4[lane];
    float2 sv = td2[node];
    float dd = sv.y;
    float a0 = dd * fmaxf(fmaf(sv.x, w1.x, bv.x), 0.f);
    float a1 = dd * fmaxf(fmaf(sv.x, w1.y, bv.y), 0.f);
    float a2 = dd * fmaxf(fmaf(sv.x, w1.z, bv.z), 0.f);
    float a3 = dd * fmaxf(fmaf(sv.x, w1.w, bv.w), 0.f);
    int e0 = row_ptr[node], e1 = row_ptr[node + 1];
    int e = e0;
    for (; e + 8 <= e1; e += 8) {
        int s0 = csr[e],     s1 = csr[e + 1], s2 = csr[e + 2], s3 = csr[e + 3];
        int s4 = csr[e + 4], s5 = csr[e + 5], s6 = csr[e + 6], s7 = csr[e + 7];
        float2 v0 = td2[s0], v1 = td2[s1], v2 = td2[s2], v3 = td2[s3];
        float2 v4 = td2[s4], v5 = td2[s5], v6 = td2[s6], v7 = td2[s7];
        a0 += ((v0.y * fmaxf(fmaf(v0.x, w1.x, bv.x), 0.f)
              + v1.y * fmaxf(fmaf(v1.x, w1.x, bv.x), 0.f))
             + (v2.y * fmaxf(fmaf(v2.x, w1.x, bv.x), 0.f)
              + v3.y * fmaxf(fmaf(v3.x, w1.x, bv.x), 0.f)))
            + ((v4.y * fmaxf(fmaf(v4.x, w1.x, bv.x), 0.f)
              + v5.y * fmaxf(fmaf(v5.x, w1.x, bv.x), 0.f))
             + (v6.y * fmaxf(fmaf(v6.x, w1.x, bv.x), 0.f)
              + v7.y * fmaxf(fmaf(v7.x, w1.x, bv.x), 0.f)));
        a1 += ((v0.y * fmaxf(fmaf(v0.x, w1.y, bv.y), 0.f)
              + v1.y * fmaxf(fmaf(v1.x, w1.y, bv.y), 0.f))
             + (v2.y * fmaxf(fmaf(v2.x, w1.y, bv.y), 0.f)
              + v3.y * fmaxf(fmaf(v3.x, w1.y, bv.y), 0.f)))
            + ((v4.y * fmaxf(fmaf(v4.x, w1.y, bv.y), 0.f)
              + v5.y * fmaxf(fmaf(v5.x, w1.y, bv.y), 0.f))
             + (v6.y * fmaxf(fmaf(v6.x, w1.y, bv.y), 0.f)
              + v7.y * fmaxf(fmaf(v7.x, w1.y, bv.y), 0.f)));
        a2 += ((v0.y * fmaxf(fmaf(v0.x, w1.z, bv.z), 0.f)
              + v1.y * fmaxf(fmaf(v1.x, w1.z, bv.z), 0.f))
             + (v2.y * fmaxf(fmaf(v2.x, w1.z, bv.z), 0.f)
              + v3.y * fmaxf(fmaf(v3.x, w1.z, bv.z), 0.f)))
            + ((v4.y * fmaxf(fmaf(v4.x, w1.z, bv.z), 0.f)
              + v5.y * fmaxf(fmaf(v5.x, w1.z, bv.z), 0.f))
             + (v6.y * fmaxf(fmaf(v6.x, w1.z, bv.z), 0.f)
              + v7.y * fmaxf(fmaf(v7.x, w1.z, bv.z), 0.f)));
        a3 += ((v0.y * fmaxf(fmaf(v0.x, w1.w, bv.w), 0.f)
              + v1.y * fmaxf(fmaf(v1.x, w1.w, bv.w), 0.f))
             + (v2.y * fmaxf(fmaf(v2.x, w1.w, bv.w), 0.f)
              + v3.y * fmaxf(fmaf(v3.x, w1.w, bv.w), 0.f)))
            + ((v4.y * fmaxf(fmaf(v4.x, w1.w, bv.w), 0.f)
              + v5.y * fmaxf(fmaf(v5.x, w1.w, bv.w), 0.f))
             + (v6.y * fmaxf(fmaf(v6.x, w1.w, bv.w), 0.f)
              + v7.y * fmaxf(fmaf(v7.x, w1.w, bv.w), 0.f)));
    }
    for (; e < e1; ++e) {
        float2 v = td2[csr[e]];
        a0 += v.y * fmaxf(fmaf(v.x, w1.x, bv.x), 0.f);
        a1 += v.y * fmaxf(fmaf(v.x, w1.y, bv.y), 0.f);
        a2 += v.y * fmaxf(fmaf(v.x, w1.z, bv.z), 0.f);
        a3 += v.y * fmaxf(fmaf(v.x, w1.w, bv.w), 0.f);
    }
    out4[(size_t)node * 32 + lane] = make_float4(a0 * dd, a1 * dd, a2 * dd, a3 * dd);
}

// out[d][:] = dis[d] * ( sum_{s in N(d)} hp[s][:] + hp[d][:] ),  F = 128
__global__ void k_agg128(const float4* __restrict__ hp4, const float* __restrict__ dis,
                         const int* __restrict__ row_ptr, const int* __restrict__ csr,
                         float4* __restrict__ out4, int N) {
    int node = blockIdx.x * 8 + (threadIdx.x >> 5);
    int lane = threadIdx.x & 31;
    if (node >= N) return;
    float4 self = hp4[(size_t)node * 32 + lane];
    float a0 = self.x, a1 = self.y, a2 = self.z, a3 = self.w;
    int e0 = row_ptr[node], e1 = row_ptr[node + 1];
    int e = e0;
    for (; e + 8 <= e1; e += 8) {
        int s0 = csr[e],     s1 = csr[e + 1], s2 = csr[e + 2], s3 = csr[e + 3];
        int s4 = csr[e + 4], s5 = csr[e + 5], s6 = csr[e + 6], s7 = csr[e + 7];
        float4 v0 = hp4[(size_t)s0 * 32 + lane];
        float4 v1 = hp4[(size_t)s1 * 32 + lane];
        float4 v2 = hp4[(size_t)s2 * 32 + lane];
        float4 v3 = hp4[(size_t)s3 * 32 + lane];
        float4 v4 = hp4[(size_t)s4 * 32 + lane];
        float4 v5 = hp4[(size_t)s5 * 32 + lane];
        float4 v6 = hp4[(size_t)s6 * 32 + lane];
        float4 v7 = hp4[(size_t)s7 * 32 + lane];
        a0 += ((v0.x + v1.x) + (v2.x + v3.x)) + ((v4.x + v5.x) + (v6.x + v7.x));
        a1 += ((v0.y + v1.y) + (v2.y + v3.y)) + ((v4.y + v5.y) + (v6.y + v7.y));
        a2 += ((v0.z + v1.z) + (v2.z + v3.z)) + ((v4.z + v5.z) + (v6.z + v7.z));
        a3 += ((v0.w + v1.w) + (v2.w + v3.w)) + ((v4.w + v5.w) + (v6.w + v7.w));
    }
    for (; e < e1; ++e) {
        int s = csr[e];
        float4 v = hp4[(size_t)s * 32 + lane];
        a0 += v.x; a1 += v.y; a2 += v.z; a3 += v.w;
    }
    float d = dis[node];
    out4[(size_t)node * 32 + lane] = make_float4(a0 * d, a1 * d, a2 * d, a3 * d);
}

// GEMM: block tile 128 nodes x 128 cols (jh), 256 threads, thread 8n x 8c
// (1.0 LDS-B/FMA, vs 1.5 at 4n x 8c -> LDS pipe no longer 1.5x oversubscribed).
// A node-major Al[128][36]; wave's 4 A-rows (ng=tid>>4 in 0..15, nodes ng+16m)
// land on distinct banks (row stride 144B => +4 banks/row). W split-column
// reads (cg*4, 64+cg*4): 2-way alias = free.
// FUSE_MAX: per-graph max-pool epilogue (relu -> shfl-reduce -> atomicMax).
template<int FOUT, bool SCALE, bool FUSE_MAX>
__global__ __launch_bounds__(256, 4) void k_gemm(
        const float* __restrict__ A, const float* __restrict__ W,
        const float* __restrict__ b, const float* __restrict__ dis,
        float* __restrict__ outp, const int* __restrict__ batch,
        unsigned int* __restrict__ gmax, int N) {
    __shared__ float Al[128][36];    // 18432 B
    __shared__ float Wl[32][132];    // 16896 B
    const int tid = threadIdx.x;
    const int n0 = blockIdx.x * 128;
    const int jh = blockIdx.y;
    const int ng = tid >> 4;   // 0..15; nodes ng + 16m, m=0..7
    const int cg = tid & 15;   // cols cg*4 + 64s + r

    float acc[8][8] = {};

    for (int kc = 0; kc < 128; kc += 32) {
        // stage A chunk: Al[nn][kk], 1024 float4 loads
        for (int it = 0; it < 4; ++it) {
            int idx = tid + it * 256;
            int nn = idx >> 3, kq = idx & 7;
            int node = n0 + nn;
            float4 a = (node < N)
                ? reinterpret_cast<const float4*>(A + (size_t)node * 128 + kc)[kq]
                : make_float4(0.f, 0.f, 0.f, 0.f);
            *reinterpret_cast<float4*>(&Al[nn][kq * 4]) = a;
        }
        // stage W chunk
        for (int it = 0; it < 4; ++it) {
            int idx = tid + it * 256;
            int kk = idx >> 5, jc = idx & 31;
            float4 w = reinterpret_cast<const float4*>(
                W + (size_t)(kc + kk) * FOUT + jh * 128)[jc];
            *reinterpret_cast<float4*>(&Wl[kk][jc * 4]) = w;
        }
        __syncthreads();

#pragma unroll
        for (int k4 = 0; k4 < 8; ++k4) {
            float4 av[8];
#pragma unroll
            for (int m = 0; m < 8; ++m)
                av[m] = *reinterpret_cast<const float4*>(&Al[ng + 16 * m][k4 * 4]);
#pragma unroll
            for (int kk = 0; kk < 4; ++kk) {
                float4 w0 = *reinterpret_cast<const float4*>(&Wl[k4 * 4 + kk][cg * 4]);
                float4 w1 = *reinterpret_cast<const float4*>(&Wl[k4 * 4 + kk][64 + cg * 4]);
                const float wv[8] = {w0.x,w0.y,w0.z,w0.w,w1.x,w1.y,w1.z,w1.w};
#pragma unroll
                for (int m = 0; m < 8; ++m) {
                    float a = (kk == 0) ? av[m].x : (kk == 1) ? av[m].y
                            : (kk == 2) ? av[m].z : av[m].w;
#pragma unroll
                    for (int j = 0; j < 8; ++j)
                        acc[m][j] = fmaf(a, wv[j], acc[m][j]);
                }
            }
        }
        __syncthreads();
    }

    if (!FUSE_MAX) {
        float bb[8];
#pragma unroll
        for (int s = 0; s < 2; ++s)
#pragma unroll
            for (int r = 0; r < 4; ++r)
                bb[s * 4 + r] = b[jh * 128 + cg * 4 + 64 * s + r];
#pragma unroll
        for (int m = 0; m < 8; ++m) {
            int node = n0 + ng + 16 * m;
            if (node < N) {
                float dsc = SCALE ? dis[node] : 1.f;
                float* op = outp + (size_t)node * FOUT + jh * 128;
#pragma unroll
                for (int s = 0; s < 2; ++s) {
                    float o[4];
#pragma unroll
                    for (int r = 0; r < 4; ++r) {
                        float v = fmaxf(acc[m][s * 4 + r] + bb[s * 4 + r], 0.f);
                        o[r] = SCALE ? v * dsc : v;
                    }
                    *reinterpret_cast<float4*>(op + cg * 4 + 64 * s) =
                        make_float4(o[0], o[1], o[2], o[3]);
                }
            }
        }
    } else {
#pragma unroll
        for (int s = 0; s < 2; ++s)
#pragma unroll
            for (int r = 0; r < 4; ++r) {
                float bv = b[jh * 128 + cg * 4 + 64 * s + r];
#pragma unroll
                for (int m = 0; m < 8; ++m)
                    acc[m][s * 4 + r] = fmaxf(acc[m][s * 4 + r] + bv, 0.f);
            }
        int nbm[8];
#pragma unroll
        for (int m = 0; m < 8; ++m) {
            int node = n0 + ng + 16 * m;
            nbm[m] = (node < N) ? batch[node] : -1;
        }
        int gfirst = batch[n0];
        int glast  = batch[min(n0 + 127, N - 1)];
        for (int gb = gfirst; gb <= glast; ++gb) {
            float mx[8];
#pragma unroll
            for (int j = 0; j < 8; ++j) mx[j] = 0.f;
#pragma unroll
            for (int m = 0; m < 8; ++m)
                if (nbm[m] == gb)
#pragma unroll
                    for (int j = 0; j < 8; ++j) mx[j] = fmaxf(mx[j], acc[m][j]);
            // reduce over the wave's 4 ng groups (lane bits 4,5)
#pragma unroll
            for (int j = 0; j < 8; ++j) {
                mx[j] = fmaxf(mx[j], __shfl_xor(mx[j], 16));
                mx[j] = fmaxf(mx[j], __shfl_xor(mx[j], 32));
            }
            if ((tid & 48) == 0) {
#pragma unroll
                for (int s = 0; s < 2; ++s)
#pragma unroll
                    for (int r = 0; r < 4; ++r)
                        atomicMax(&gmax[gb * 256 + jh * 128 + cg * 4 + 64 * s + r],
                                  __float_as_uint(mx[s * 4 + r]));
            }
        }
    }
}

// final MLP: out = relu( relu(g@Wf1+bf1) @ Wf2 + bf2 )
__global__ void k_mlp(const float* __restrict__ g, const float* __restrict__ Wf1,
                      const float* __restrict__ bf1, const float* __restrict__ Wf2,
                      const float* __restrict__ bf2, float* __restrict__ out) {
    __shared__ float gr[256];
    __shared__ float g1s[128];
    const int gid = blockIdx.x;
    const int tid = threadIdx.x;
    gr[tid] = g[gid * 256 + tid];
    gr[tid + 128] = g[gid * 256 + 128 + tid];
    __syncthreads();
    float acc = bf1[tid];
    for (int k = 0; k < 256; ++k)
        acc = fmaf(gr[k], Wf1[k * 128 + tid], acc);
    g1s[tid] = fmaxf(acc, 0.f);
    __syncthreads();
    if (tid < 10) {
        float a = bf2[tid];
        for (int k = 0; k < 128; ++k)
            a = fmaf(g1s[k], Wf2[k * 10 + tid], a);
        out[gid * 10 + tid] = fmaxf(a, 0.f);
    }
}

// ---------------------------------------------------------------------------
extern "C" void kernel_launch(void* const* d_in, const int* in_sizes, int n_in,
                              void* d_out, int out_size, void* d_ws, size_t ws_size,
                              hipStream_t stream) {
    const float* x   = (const float*)d_in[0];
    const int*   ei  = (const int*)d_in[1];
    const int*   bat = (const int*)d_in[2];
    const float* W1  = (const float*)d_in[3];
    const float* b1  = (const float*)d_in[4];
    const float* W2  = (const float*)d_in[5];
    const float* b2  = (const float*)d_in[6];
    const float* W3  = (const float*)d_in[7];
    const float* b3  = (const float*)d_in[8];
    const float* Wf1 = (const float*)d_in[9];
    const float* bf1 = (const float*)d_in[10];
    const float* Wf2 = (const float*)d_in[11];
    const float* bf2 = (const float*)d_in[12];
    float* out = (float*)d_out;

    const int N = in_sizes[0];          // 50000
    const int E = in_sizes[1] / 2;      // 800000
    const int* src = ei;
    const int* dst = ei + E;

    char* base = (char*)d_ws;
    size_t off = 0;
    auto carve = [&](size_t bytes) -> char* {
        char* p = base + off;
        off = (off + bytes + 255) & ~(size_t)255;
        return p;
    };
    const int nb = (N + 255) / 256;
    int*    deg     = (int*)   carve((size_t)N * 4);
    int*    fill    = (int*)   carve((size_t)N * 4);
    int*    row_ptr = (int*)   carve((size_t)(N + 1) * 4);
    int*    csr     = (int*)   carve((size_t)E * 4);
    float*  dis     = (float*) carve((size_t)N * 4);
    float*  xp      = (float*) carve((size_t)N * 4);
    float2* td2     = (float2*)carve((size_t)N * 8);
    float*  A2      = (float*) carve((size_t)N * 128 * 4);
    float*  B2      = (float*) carve((size_t)N * 128 * 4);
    float*  A3      = (float*) carve((size_t)N * 128 * 4);
    unsigned int* g = (unsigned int*)carve((size_t)N_GRAPHS * 256 * 4);
    int*    bsum    = (int*)   carve((size_t)nb * 4);
    int*    boff    = (int*)   carve((size_t)nb * 4);
    (void)ws_size; (void)n_in; (void)out_size;

    hipMemsetAsync(deg, 0, (size_t)N * 4, stream);
    hipMemsetAsync(fill, 0, (size_t)N * 4, stream);
    hipMemsetAsync(g, 0, (size_t)N_GRAPHS * 256 * 4, stream);

    int eb = (E + 255) / 256;

    k_deg<<<eb, 256, 0, stream>>>(dst, E, deg);
    k_dis_bsum<<<nb, 256, 0, stream>>>(deg, x, dis, xp, bsum, N);
    k_scan_sums<<<1, 256, 0, stream>>>(bsum, nb, boff);
    k_scan_apply<<<nb, 256, 0, stream>>>(deg, boff, row_ptr, N);
    k_scatter<<<eb, 256, 0, stream>>>(src, dst, E, row_ptr, fill, csr);

    k_agg_scalar<<<nb, 256, 0, stream>>>(xp, dis, row_ptr, csr, td2, N);

    const int gx = (N + 127) / 128;
    const int ab = (N + 7) / 8;

    // layer 1+2: recompute-gather h1 -> A2 (LDS-free), then GEMM W2 -> B2
    k_h1agg<<<ab, 256, 0, stream>>>(td2, (const float4*)W1, (const float4*)b1,
                                    row_ptr, csr, (float4*)A2, N);
    k_gemm<128, true, false><<<dim3(gx, 1), 256, 0, stream>>>(
        A2, W2, b2, dis, B2, nullptr, nullptr, N);

    // layer 3: row-gather aggregation, then GEMM W3 + fused max-pool
    k_agg128<<<ab, 256, 0, stream>>>((const float4*)B2, dis, row_ptr, csr,
                                     (float4*)A3, N);
    k_gemm<256, false, true><<<dim3(gx, 2), 256, 0, stream>>>(
        A3, W3, b3, nullptr, nullptr, bat, g, N);

    k_mlp<<<N_GRAPHS, 128, 0, stream>>>((const float*)g, Wf1, bf1, Wf2, bf2, out);
}

// Round 10
// 288.402 us; speedup vs baseline: 1.0785x; 1.0785x over previous
//
#include <hip/hip_runtime.h>
#include <hip/hip_bf16.h>

#define N_GRAPHS 64

// ---------------------------------------------------------------------------
__global__ void k_deg(const int* __restrict__ dst, int E, int* __restrict__ deg) {
    int i = blockIdx.x * blockDim.x + threadIdx.x;
    if (i < E) atomicAdd(&deg[dst[i]], 1);
}

// dis/xp + per-block deg sums (fused)
__global__ void k_dis_bsum(const int* __restrict__ deg, const float* __restrict__ x,
                           float* __restrict__ dis, float* __restrict__ xp,
                           int* __restrict__ bsum, int N) {
    int i = blockIdx.x * 256 + threadIdx.x;
    int dv = (i < N) ? deg[i] : 0;
    if (i < N) {
        float d = rsqrtf((float)(dv + 1));
        dis[i] = d;
        xp[i]  = d * x[i];
    }
    int v = dv;
#pragma unroll
    for (int o = 1; o < 64; o <<= 1) v += __shfl_xor(v, o);
    __shared__ int ws4[4];
    if ((threadIdx.x & 63) == 0) ws4[threadIdx.x >> 6] = v;
    __syncthreads();
    if (threadIdx.x == 0) bsum[blockIdx.x] = ws4[0] + ws4[1] + ws4[2] + ws4[3];
}

__device__ inline int block_scan_inc(int v, int* wsum) {
    int lane = threadIdx.x & 63, w = threadIdx.x >> 6;
    int iv = v;
#pragma unroll
    for (int o = 1; o < 64; o <<= 1) {
        int t = __shfl_up(iv, o);
        if (lane >= o) iv += t;
    }
    if (lane == 63) wsum[w] = iv;
    __syncthreads();
    int add = 0;
    for (int k = 0; k < w; ++k) add += wsum[k];
    return iv + add;
}

__global__ void k_scan_sums(const int* __restrict__ bsum, int nb, int* __restrict__ boff) {
    __shared__ int wsum[4];
    int tid = threadIdx.x;
    int v = (tid < nb) ? bsum[tid] : 0;
    int inc = block_scan_inc(v, wsum);
    if (tid < nb) boff[tid] = inc - v;   // exclusive
}

__global__ void k_scan_apply(const int* __restrict__ deg, const int* __restrict__ boff,
                             int* __restrict__ row_ptr, int N) {
    __shared__ int wsum[4];
    int b = blockIdx.x, i = b * 256 + threadIdx.x;
    int v = (i < N) ? deg[i] : 0;
    int inc = block_scan_inc(v, wsum) + boff[b];
    if (i < N) {
        row_ptr[i] = inc - v;
        if (i == N - 1) row_ptr[N] = inc;
    }
}

__global__ void k_scatter(const int* __restrict__ src, const int* __restrict__ dst, int E,
                          const int* __restrict__ row_ptr, int* __restrict__ fill,
                          int* __restrict__ csr_src) {
    int e = blockIdx.x * blockDim.x + threadIdx.x;
    if (e < E) {
        int d = dst[e];
        int pos = row_ptr[d] + atomicAdd(&fill[d], 1);
        csr_src[pos] = src[e];
    }
}

// td2[d] = ( dis[d] * (sum xp[s] + xp[d]),  dis[d] )
__global__ void k_agg_scalar(const float* __restrict__ xp, const float* __restrict__ dis,
                             const int* __restrict__ row_ptr, const int* __restrict__ csr,
                             float2* __restrict__ td2, int N) {
    int d = blockIdx.x * blockDim.x + threadIdx.x;
    if (d >= N) return;
    float acc = xp[d];
    int e0 = row_ptr[d], e1 = row_ptr[d + 1];
    int e = e0;
    for (; e + 8 <= e1; e += 8) {
        int s0 = csr[e],     s1 = csr[e + 1], s2 = csr[e + 2], s3 = csr[e + 3];
        int s4 = csr[e + 4], s5 = csr[e + 5], s6 = csr[e + 6], s7 = csr[e + 7];
        acc += ((xp[s0] + xp[s1]) + (xp[s2] + xp[s3]))
             + ((xp[s4] + xp[s5]) + (xp[s6] + xp[s7]));
    }
    for (; e < e1; ++e) acc += xp[csr[e]];
    float dd = dis[d];
    td2[d] = make_float2(dd * acc, dd);
}

// ---------------------------------------------------------------------------
// Layer-2 aggregation with rank-1 h1 recompute (LDS-free, high occupancy)
__global__ void k_h1agg(const float2* __restrict__ td2,
                        const float4* __restrict__ W1f4, const float4* __restrict__ b1f4,
                        const int* __restrict__ row_ptr, const int* __restrict__ csr,
                        float4* __restrict__ out4, int N) {
    int node = blockIdx.x * 8 + (threadIdx.x >> 5);
    int lane = threadIdx.x & 31;
    if (node >= N) return;
    const float4 w1 = W1f4[lane];
    const float4 bv = b1f4[lane];
    float2 sv = td2[node];
    float dd = sv.y;
    float a0 = dd * fmaxf(fmaf(sv.x, w1.x, bv.x), 0.f);
    float a1 = dd * fmaxf(fmaf(sv.x, w1.y, bv.y), 0.f);
    float a2 = dd * fmaxf(fmaf(sv.x, w1.z, bv.z), 0.f);
    float a3 = dd * fmaxf(fmaf(sv.x, w1.w, bv.w), 0.f);
    int e0 = row_ptr[node], e1 = row_ptr[node + 1];
    int e = e0;
    for (; e + 8 <= e1; e += 8) {
        int s0 = csr[e],     s1 = csr[e + 1], s2 = csr[e + 2], s3 = csr[e + 3];
        int s4 = csr[e + 4], s5 = csr[e + 5], s6 = csr[e + 6], s7 = csr[e + 7];
        float2 v0 = td2[s0], v1 = td2[s1], v2 = td2[s2], v3 = td2[s3];
        float2 v4 = td2[s4], v5 = td2[s5], v6 = td2[s6], v7 = td2[s7];
        a0 += ((v0.y * fmaxf(fmaf(v0.x, w1.x, bv.x), 0.f)
              + v1.y * fmaxf(fmaf(v1.x, w1.x, bv.x), 0.f))
             + (v2.y * fmaxf(fmaf(v2.x, w1.x, bv.x), 0.f)
              + v3.y * fmaxf(fmaf(v3.x, w1.x, bv.x), 0.f)))
            + ((v4.y * fmaxf(fmaf(v4.x, w1.x, bv.x), 0.f)
              + v5.y * fmaxf(fmaf(v5.x, w1.x, bv.x), 0.f))
             + (v6.y * fmaxf(fmaf(v6.x, w1.x, bv.x), 0.f)
              + v7.y * fmaxf(fmaf(v7.x, w1.x, bv.x), 0.f)));
        a1 += ((v0.y * fmaxf(fmaf(v0.x, w1.y, bv.y), 0.f)
              + v1.y * fmaxf(fmaf(v1.x, w1.y, bv.y), 0.f))
             + (v2.y * fmaxf(fmaf(v2.x, w1.y, bv.y), 0.f)
              + v3.y * fmaxf(fmaf(v3.x, w1.y, bv.y), 0.f)))
            + ((v4.y * fmaxf(fmaf(v4.x, w1.y, bv.y), 0.f)
              + v5.y * fmaxf(fmaf(v5.x, w1.y, bv.y), 0.f))
             + (v6.y * fmaxf(fmaf(v6.x, w1.y, bv.y), 0.f)
              + v7.y * fmaxf(fmaf(v7.x, w1.y, bv.y), 0.f)));
        a2 += ((v0.y * fmaxf(fmaf(v0.x, w1.z, bv.z), 0.f)
              + v1.y * fmaxf(fmaf(v1.x, w1.z, bv.z), 0.f))
             + (v2.y * fmaxf(fmaf(v2.x, w1.z, bv.z), 0.f)
              + v3.y * fmaxf(fmaf(v3.x, w1.z, bv.z), 0.f)))
            + ((v4.y * fmaxf(fmaf(v4.x, w1.z, bv.z), 0.f)
              + v5.y * fmaxf(fmaf(v5.x, w1.z, bv.z), 0.f))
             + (v6.y * fmaxf(fmaf(v6.x, w1.z, bv.z), 0.f)
              + v7.y * fmaxf(fmaf(v7.x, w1.z, bv.z), 0.f)));
        a3 += ((v0.y * fmaxf(fmaf(v0.x, w1.w, bv.w), 0.f)
              + v1.y * fmaxf(fmaf(v1.x, w1.w, bv.w), 0.f))
             + (v2.y * fmaxf(fmaf(v2.x, w1.w, bv.w), 0.f)
              + v3.y * fmaxf(fmaf(v3.x, w1.w, bv.w), 0.f)))
            + ((v4.y * fmaxf(fmaf(v4.x, w1.w, bv.w), 0.f)
              + v5.y * fmaxf(fmaf(v5.x, w1.w, bv.w), 0.f))
             + (v6.y * fmaxf(fmaf(v6.x, w1.w, bv.w), 0.f)
              + v7.y * fmaxf(fmaf(v7.x, w1.w, bv.w), 0.f)));
    }
    for (; e < e1; ++e) {
        float2 v = td2[csr[e]];
        a0 += v.y * fmaxf(fmaf(v.x, w1.x, bv.x), 0.f);
        a1 += v.y * fmaxf(fmaf(v.x, w1.y, bv.y), 0.f);
        a2 += v.y * fmaxf(fmaf(v.x, w1.z, bv.z), 0.f);
        a3 += v.y * fmaxf(fmaf(v.x, w1.w, bv.w), 0.f);
    }
    out4[(size_t)node * 32 + lane] = make_float4(a0 * dd, a1 * dd, a2 * dd, a3 * dd);
}

// out[d][:] = dis[d] * ( sum_{s in N(d)} hp[s][:] + hp[d][:] ),  F = 128
__global__ void k_agg128(const float4* __restrict__ hp4, const float* __restrict__ dis,
                         const int* __restrict__ row_ptr, const int* __restrict__ csr,
                         float4* __restrict__ out4, int N) {
    int node = blockIdx.x * 8 + (threadIdx.x >> 5);
    int lane = threadIdx.x & 31;
    if (node >= N) return;
    float4 self = hp4[(size_t)node * 32 + lane];
    float a0 = self.x, a1 = self.y, a2 = self.z, a3 = self.w;
    int e0 = row_ptr[node], e1 = row_ptr[node + 1];
    int e = e0;
    for (; e + 8 <= e1; e += 8) {
        int s0 = csr[e],     s1 = csr[e + 1], s2 = csr[e + 2], s3 = csr[e + 3];
        int s4 = csr[e + 4], s5 = csr[e + 5], s6 = csr[e + 6], s7 = csr[e + 7];
        float4 v0 = hp4[(size_t)s0 * 32 + lane];
        float4 v1 = hp4[(size_t)s1 * 32 + lane];
        float4 v2 = hp4[(size_t)s2 * 32 + lane];
        float4 v3 = hp4[(size_t)s3 * 32 + lane];
        float4 v4 = hp4[(size_t)s4 * 32 + lane];
        float4 v5 = hp4[(size_t)s5 * 32 + lane];
        float4 v6 = hp4[(size_t)s6 * 32 + lane];
        float4 v7 = hp4[(size_t)s7 * 32 + lane];
        a0 += ((v0.x + v1.x) + (v2.x + v3.x)) + ((v4.x + v5.x) + (v6.x + v7.x));
        a1 += ((v0.y + v1.y) + (v2.y + v3.y)) + ((v4.y + v5.y) + (v6.y + v7.y));
        a2 += ((v0.z + v1.z) + (v2.z + v3.z)) + ((v4.z + v5.z) + (v6.z + v7.z));
        a3 += ((v0.w + v1.w) + (v2.w + v3.w)) + ((v4.w + v5.w) + (v6.w + v7.w));
    }
    for (; e < e1; ++e) {
        int s = csr[e];
        float4 v = hp4[(size_t)s * 32 + lane];
        a0 += v.x; a1 += v.y; a2 += v.z; a3 += v.w;
    }
    float d = dis[node];
    out4[(size_t)node * 32 + lane] = make_float4(a0 * d, a1 * d, a2 * d, a3 * d);
}

// GEMM: 128 threads, tile 64 nodes x 128 cols (jh), thread tile 8n x 8c.
// A transposed in LDS At[k][n] (conflict-free b128 reads of 4 consecutive
// nodes); W split-column reads (2-way alias = free). Per k per wave:
// 4 ds_read_b128 per 64 FMA-instr -> LDS pipe no longer the limiter.
// LDS 25.6KB -> 6 blocks/CU (12 waves/CU) at 128 threads; grid 782+.
// FUSE_MAX: per-graph max-pool epilogue (relu -> shfl-reduce -> atomicMax).
template<int FOUT, bool SCALE, bool FUSE_MAX>
__global__ __launch_bounds__(128, 3) void k_gemm(
        const float* __restrict__ A, const float* __restrict__ W,
        const float* __restrict__ b, const float* __restrict__ dis,
        float* __restrict__ outp, const int* __restrict__ batch,
        unsigned int* __restrict__ gmax, int N) {
    __shared__ float At[32][68];     // 8704 B,  At[kk][nn]
    __shared__ float Wl[32][132];    // 16896 B, Wl[kk][j]
    const int tid = threadIdx.x;
    const int n0 = blockIdx.x * 64;
    const int jh = blockIdx.y;
    const int ng = tid >> 4;   // 0..7 -> nodes ng*8 .. +7
    const int cg = tid & 15;   // cols cg*4 + {0..3} u 64+cg*4 + {0..3}

    float acc[8][8] = {};

    for (int kc = 0; kc < 128; kc += 32) {
        // stage A^T chunk: coalesced loads (kq lane-fastest), transpose write
#pragma unroll
        for (int it = 0; it < 4; ++it) {
            int idx = tid + it * 128;
            int kq = idx & 7, nn = idx >> 3;
            int node = n0 + nn;
            float4 a = (node < N)
                ? reinterpret_cast<const float4*>(A + (size_t)node * 128 + kc)[kq]
                : make_float4(0.f, 0.f, 0.f, 0.f);
            At[kq * 4 + 0][nn] = a.x;
            At[kq * 4 + 1][nn] = a.y;
            At[kq * 4 + 2][nn] = a.z;
            At[kq * 4 + 3][nn] = a.w;
        }
        // stage W chunk (jc lane-fastest: coalesced)
#pragma unroll
        for (int it = 0; it < 8; ++it) {
            int idx = tid + it * 128;
            int kk = idx >> 5, jc = idx & 31;
            float4 w = reinterpret_cast<const float4*>(
                W + (size_t)(kc + kk) * FOUT + jh * 128)[jc];
            *reinterpret_cast<float4*>(&Wl[kk][jc * 4]) = w;
        }
        __syncthreads();

#pragma unroll 8
        for (int k = 0; k < 32; ++k) {
            float4 a0 = *reinterpret_cast<const float4*>(&At[k][ng * 8]);
            float4 a1 = *reinterpret_cast<const float4*>(&At[k][ng * 8 + 4]);
            float4 w0 = *reinterpret_cast<const float4*>(&Wl[k][cg * 4]);
            float4 w1 = *reinterpret_cast<const float4*>(&Wl[k][64 + cg * 4]);
            const float av[8] = {a0.x,a0.y,a0.z,a0.w,a1.x,a1.y,a1.z,a1.w};
            const float wv[8] = {w0.x,w0.y,w0.z,w0.w,w1.x,w1.y,w1.z,w1.w};
#pragma unroll
            for (int m = 0; m < 8; ++m)
#pragma unroll
                for (int j = 0; j < 8; ++j)
                    acc[m][j] = fmaf(av[m], wv[j], acc[m][j]);
        }
        __syncthreads();
    }

    if (!FUSE_MAX) {
        float bb[8];
#pragma unroll
        for (int s = 0; s < 2; ++s)
#pragma unroll
            for (int r = 0; r < 4; ++r)
                bb[s * 4 + r] = b[jh * 128 + cg * 4 + 64 * s + r];
#pragma unroll
        for (int m = 0; m < 8; ++m) {
            int node = n0 + ng * 8 + m;
            if (node < N) {
                float dsc = SCALE ? dis[node] : 1.f;
                float* op = outp + (size_t)node * FOUT + jh * 128;
#pragma unroll
                for (int s = 0; s < 2; ++s) {
                    float o[4];
#pragma unroll
                    for (int r = 0; r < 4; ++r) {
                        float v = fmaxf(acc[m][s * 4 + r] + bb[s * 4 + r], 0.f);
                        o[r] = SCALE ? v * dsc : v;
                    }
                    *reinterpret_cast<float4*>(op + cg * 4 + 64 * s) =
                        make_float4(o[0], o[1], o[2], o[3]);
                }
            }
        }
    } else {
        // relu(+bias) in registers, then per-graph max -> atomicMax
#pragma unroll
        for (int s = 0; s < 2; ++s)
#pragma unroll
            for (int r = 0; r < 4; ++r) {
                float bv = b[jh * 128 + cg * 4 + 64 * s + r];
#pragma unroll
                for (int m = 0; m < 8; ++m)
                    acc[m][s * 4 + r] = fmaxf(acc[m][s * 4 + r] + bv, 0.f);
            }
        int nbm[8];
#pragma unroll
        for (int m = 0; m < 8; ++m) {
            int node = n0 + ng * 8 + m;
            nbm[m] = (node < N) ? batch[node] : -1;
        }
        int gfirst = batch[n0];
        int glast  = batch[min(n0 + 63, N - 1)];
        for (int gb = gfirst; gb <= glast; ++gb) {
            float mx[8];
#pragma unroll
            for (int j = 0; j < 8; ++j) mx[j] = 0.f;
#pragma unroll
            for (int m = 0; m < 8; ++m)
                if (nbm[m] == gb)
#pragma unroll
                    for (int j = 0; j < 8; ++j) mx[j] = fmaxf(mx[j], acc[m][j]);
            // reduce over the wave's 4 ng-groups (lane bits 4,5)
#pragma unroll
            for (int j = 0; j < 8; ++j) {
                mx[j] = fmaxf(mx[j], __shfl_xor(mx[j], 16));
                mx[j] = fmaxf(mx[j], __shfl_xor(mx[j], 32));
            }
            if ((tid & 48) == 0) {   // one cg-lane set per wave
#pragma unroll
                for (int s = 0; s < 2; ++s)
#pragma unroll
                    for (int r = 0; r < 4; ++r)
                        atomicMax(&gmax[gb * 256 + jh * 128 + cg * 4 + 64 * s + r],
                                  __float_as_uint(mx[s * 4 + r]));
            }
        }
    }
}

// final MLP: out = relu( relu(g@Wf1+bf1) @ Wf2 + bf2 )
__global__ void k_mlp(const float* __restrict__ g, const float* __restrict__ Wf1,
                      const float* __restrict__ bf1, const float* __restrict__ Wf2,
                      const float* __restrict__ bf2, float* __restrict__ out) {
    __shared__ float gr[256];
    __shared__ float g1s[128];
    const int gid = blockIdx.x;
    const int tid = threadIdx.x;
    gr[tid] = g[gid * 256 + tid];
    gr[tid + 128] = g[gid * 256 + 128 + tid];
    __syncthreads();
    float acc = bf1[tid];
    for (int k = 0; k < 256; ++k)
        acc = fmaf(gr[k], Wf1[k * 128 + tid], acc);
    g1s[tid] = fmaxf(acc, 0.f);
    __syncthreads();
    if (tid < 10) {
        float a = bf2[tid];
        for (int k = 0; k < 128; ++k)
            a = fmaf(g1s[k], Wf2[k * 10 + tid], a);
        out[gid * 10 + tid] = fmaxf(a, 0.f);
    }
}

// ---------------------------------------------------------------------------
extern "C" void kernel_launch(void* const* d_in, const int* in_sizes, int n_in,
                              void* d_out, int out_size, void* d_ws, size_t ws_size,
                              hipStream_t stream) {
    const float* x   = (const float*)d_in[0];
    const int*   ei  = (const int*)d_in[1];
    const int*   bat = (const int*)d_in[2];
    const float* W1  = (const float*)d_in[3];
    const float* b1  = (const float*)d_in[4];
    const float* W2  = (const float*)d_in[5];
    const float* b2  = (const float*)d_in[6];
    const float* W3  = (const float*)d_in[7];
    const float* b3  = (const float*)d_in[8];
    const float* Wf1 = (const float*)d_in[9];
    const float* bf1 = (const float*)d_in[10];
    const float* Wf2 = (const float*)d_in[11];
    const float* bf2 = (const float*)d_in[12];
    float* out = (float*)d_out;

    const int N = in_sizes[0];          // 50000
    const int E = in_sizes[1] / 2;      // 800000
    const int* src = ei;
    const int* dst = ei + E;

    char* base = (char*)d_ws;
    size_t off = 0;
    auto carve = [&](size_t bytes) -> char* {
        char* p = base + off;
        off = (off + bytes + 255) & ~(size_t)255;
        return p;
    };
    const int nb = (N + 255) / 256;
    int*    deg     = (int*)   carve((size_t)N * 4);
    int*    fill    = (int*)   carve((size_t)N * 4);
    int*    row_ptr = (int*)   carve((size_t)(N + 1) * 4);
    int*    csr     = (int*)   carve((size_t)E * 4);
    float*  dis     = (float*) carve((size_t)N * 4);
    float*  xp      = (float*) carve((size_t)N * 4);
    float2* td2     = (float2*)carve((size_t)N * 8);
    float*  A2      = (float*) carve((size_t)N * 128 * 4);
    float*  B2      = (float*) carve((size_t)N * 128 * 4);
    float*  A3      = (float*) carve((size_t)N * 128 * 4);
    unsigned int* g = (unsigned int*)carve((size_t)N_GRAPHS * 256 * 4);
    int*    bsum    = (int*)   carve((size_t)nb * 4);
    int*    boff    = (int*)   carve((size_t)nb * 4);
    (void)ws_size; (void)n_in; (void)out_size;

    hipMemsetAsync(deg, 0, (size_t)N * 4, stream);
    hipMemsetAsync(fill, 0, (size_t)N * 4, stream);
    hipMemsetAsync(g, 0, (size_t)N_GRAPHS * 256 * 4, stream);

    int eb = (E + 255) / 256;

    k_deg<<<eb, 256, 0, stream>>>(dst, E, deg);
    k_dis_bsum<<<nb, 256, 0, stream>>>(deg, x, dis, xp, bsum, N);
    k_scan_sums<<<1, 256, 0, stream>>>(bsum, nb, boff);
    k_scan_apply<<<nb, 256, 0, stream>>>(deg, boff, row_ptr, N);
    k_scatter<<<eb, 256, 0, stream>>>(src, dst, E, row_ptr, fill, csr);

    k_agg_scalar<<<nb, 256, 0, stream>>>(xp, dis, row_ptr, csr, td2, N);

    const int gx = (N + 63) / 64;
    const int ab = (N + 7) / 8;

    // layer 1+2: recompute-gather h1 -> A2 (LDS-free), then GEMM W2 -> B2
    k_h1agg<<<ab, 256, 0, stream>>>(td2, (const float4*)W1, (const float4*)b1,
                                    row_ptr, csr, (float4*)A2, N);
    k_gemm<128, true, false><<<dim3(gx, 1), 128, 0, stream>>>(
        A2, W2, b2, dis, B2, nullptr, nullptr, N);

    // layer 3: row-gather aggregation, then GEMM W3 + fused max-pool
    k_agg128<<<ab, 256, 0, stream>>>((const float4*)B2, dis, row_ptr, csr,
                                     (float4*)A3, N);
    k_gemm<256, false, true><<<dim3(gx, 2), 128, 0, stream>>>(
        A3, W3, b3, nullptr, nullptr, bat, g, N);

    k_mlp<<<N_GRAPHS, 128, 0, stream>>>((const float*)g, Wf1, bf1, Wf2, bf2, out);
}

// Round 11
// 250.139 us; speedup vs baseline: 1.2434x; 1.1530x over previous
//
#include <hip/hip_runtime.h>
#include <hip/hip_bf16.h>

#define N_GRAPHS 64

typedef float f32x4 __attribute__((ext_vector_type(4)));
typedef short bf16x8 __attribute__((ext_vector_type(8)));

__device__ inline unsigned short f2bf(float f) {   // fp32 -> bf16 RNE
    unsigned int u = __float_as_uint(f);
    u = u + 0x7fffu + ((u >> 16) & 1u);
    return (unsigned short)(u >> 16);
}
__device__ inline float bf2f(unsigned short h) {
    return __uint_as_float(((unsigned int)h) << 16);
}

// ---------------------------------------------------------------------------
__global__ void k_deg(const int* __restrict__ dst, int E, int* __restrict__ deg) {
    int i = blockIdx.x * blockDim.x + threadIdx.x;
    if (i < E) atomicAdd(&deg[dst[i]], 1);
}

__global__ void k_dis_bsum(const int* __restrict__ deg, const float* __restrict__ x,
                           float* __restrict__ dis, float* __restrict__ xp,
                           int* __restrict__ bsum, int N) {
    int i = blockIdx.x * 256 + threadIdx.x;
    int dv = (i < N) ? deg[i] : 0;
    if (i < N) {
        float d = rsqrtf((float)(dv + 1));
        dis[i] = d;
        xp[i]  = d * x[i];
    }
    int v = dv;
#pragma unroll
    for (int o = 1; o < 64; o <<= 1) v += __shfl_xor(v, o);
    __shared__ int ws4[4];
    if ((threadIdx.x & 63) == 0) ws4[threadIdx.x >> 6] = v;
    __syncthreads();
    if (threadIdx.x == 0) bsum[blockIdx.x] = ws4[0] + ws4[1] + ws4[2] + ws4[3];
}

__device__ inline int block_scan_inc(int v, int* wsum) {
    int lane = threadIdx.x & 63, w = threadIdx.x >> 6;
    int iv = v;
#pragma unroll
    for (int o = 1; o < 64; o <<= 1) {
        int t = __shfl_up(iv, o);
        if (lane >= o) iv += t;
    }
    if (lane == 63) wsum[w] = iv;
    __syncthreads();
    int add = 0;
    for (int k = 0; k < w; ++k) add += wsum[k];
    return iv + add;
}

__global__ void k_scan_sums(const int* __restrict__ bsum, int nb, int* __restrict__ boff) {
    __shared__ int wsum[4];
    int tid = threadIdx.x;
    int v = (tid < nb) ? bsum[tid] : 0;
    int inc = block_scan_inc(v, wsum);
    if (tid < nb) boff[tid] = inc - v;
}

__global__ void k_scan_apply(const int* __restrict__ deg, const int* __restrict__ boff,
                             int* __restrict__ row_ptr, int N) {
    __shared__ int wsum[4];
    int b = blockIdx.x, i = b * 256 + threadIdx.x;
    int v = (i < N) ? deg[i] : 0;
    int inc = block_scan_inc(v, wsum) + boff[b];
    if (i < N) {
        row_ptr[i] = inc - v;
        if (i == N - 1) row_ptr[N] = inc;
    }
}

__global__ void k_scatter(const int* __restrict__ src, const int* __restrict__ dst, int E,
                          const int* __restrict__ row_ptr, int* __restrict__ fill,
                          int* __restrict__ csr_src) {
    int e = blockIdx.x * blockDim.x + threadIdx.x;
    if (e < E) {
        int d = dst[e];
        int pos = row_ptr[d] + atomicAdd(&fill[d], 1);
        csr_src[pos] = src[e];
    }
}

// td2[d] = ( dis[d] * (sum xp[s] + xp[d]),  dis[d] )
__global__ void k_agg_scalar(const float* __restrict__ xp, const float* __restrict__ dis,
                             const int* __restrict__ row_ptr, const int* __restrict__ csr,
                             float2* __restrict__ td2, int N) {
    int d = blockIdx.x * blockDim.x + threadIdx.x;
    if (d >= N) return;
    float acc = xp[d];
    int e0 = row_ptr[d], e1 = row_ptr[d + 1];
    int e = e0;
    for (; e + 8 <= e1; e += 8) {
        int s0 = csr[e],     s1 = csr[e + 1], s2 = csr[e + 2], s3 = csr[e + 3];
        int s4 = csr[e + 4], s5 = csr[e + 5], s6 = csr[e + 6], s7 = csr[e + 7];
        acc += ((xp[s0] + xp[s1]) + (xp[s2] + xp[s3]))
             + ((xp[s4] + xp[s5]) + (xp[s6] + xp[s7]));
    }
    for (; e < e1; ++e) acc += xp[csr[e]];
    float dd = dis[d];
    td2[d] = make_float2(dd * acc, dd);
}

// ---------------------------------------------------------------------------
// Layer-2 aggregation with rank-1 h1 recompute (LDS-free, high occupancy)
__global__ void k_h1agg(const float2* __restrict__ td2,
                        const float4* __restrict__ W1f4, const float4* __restrict__ b1f4,
                        const int* __restrict__ row_ptr, const int* __restrict__ csr,
                        float4* __restrict__ out4, int N) {
    int node = blockIdx.x * 8 + (threadIdx.x >> 5);
    int lane = threadIdx.x & 31;
    if (node >= N) return;
    const float4 w1 = W1f4[lane];
    const float4 bv = b1f4[lane];
    float2 sv = td2[node];
    float dd = sv.y;
    float a0 = dd * fmaxf(fmaf(sv.x, w1.x, bv.x), 0.f);
    float a1 = dd * fmaxf(fmaf(sv.x, w1.y, bv.y), 0.f);
    float a2 = dd * fmaxf(fmaf(sv.x, w1.z, bv.z), 0.f);
    float a3 = dd * fmaxf(fmaf(sv.x, w1.w, bv.w), 0.f);
    int e0 = row_ptr[node], e1 = row_ptr[node + 1];
    int e = e0;
    for (; e + 8 <= e1; e += 8) {
        int s0 = csr[e],     s1 = csr[e + 1], s2 = csr[e + 2], s3 = csr[e + 3];
        int s4 = csr[e + 4], s5 = csr[e + 5], s6 = csr[e + 6], s7 = csr[e + 7];
        float2 v0 = td2[s0], v1 = td2[s1], v2 = td2[s2], v3 = td2[s3];
        float2 v4 = td2[s4], v5 = td2[s5], v6 = td2[s6], v7 = td2[s7];
        a0 += ((v0.y * fmaxf(fmaf(v0.x, w1.x, bv.x), 0.f)
              + v1.y * fmaxf(fmaf(v1.x, w1.x, bv.x), 0.f))
             + (v2.y * fmaxf(fmaf(v2.x, w1.x, bv.x), 0.f)
              + v3.y * fmaxf(fmaf(v3.x, w1.x, bv.x), 0.f)))
            + ((v4.y * fmaxf(fmaf(v4.x, w1.x, bv.x), 0.f)
              + v5.y * fmaxf(fmaf(v5.x, w1.x, bv.x), 0.f))
             + (v6.y * fmaxf(fmaf(v6.x, w1.x, bv.x), 0.f)
              + v7.y * fmaxf(fmaf(v7.x, w1.x, bv.x), 0.f)));
        a1 += ((v0.y * fmaxf(fmaf(v0.x, w1.y, bv.y), 0.f)
              + v1.y * fmaxf(fmaf(v1.x, w1.y, bv.y), 0.f))
             + (v2.y * fmaxf(fmaf(v2.x, w1.y, bv.y), 0.f)
              + v3.y * fmaxf(fmaf(v3.x, w1.y, bv.y), 0.f)))
            + ((v4.y * fmaxf(fmaf(v4.x, w1.y, bv.y), 0.f)
              + v5.y * fmaxf(fmaf(v5.x, w1.y, bv.y), 0.f))
             + (v6.y * fmaxf(fmaf(v6.x, w1.y, bv.y), 0.f)
              + v7.y * fmaxf(fmaf(v7.x, w1.y, bv.y), 0.f)));
        a2 += ((v0.y * fmaxf(fmaf(v0.x, w1.z, bv.z), 0.f)
              + v1.y * fmaxf(fmaf(v1.x, w1.z, bv.z), 0.f))
             + (v2.y * fmaxf(fmaf(v2.x, w1.z, bv.z), 0.f)
              + v3.y * fmaxf(fmaf(v3.x, w1.z, bv.z), 0.f)))
            + ((v4.y * fmaxf(fmaf(v4.x, w1.z, bv.z), 0.f)
              + v5.y * fmaxf(fmaf(v5.x, w1.z, bv.z), 0.f))
             + (v6.y * fmaxf(fmaf(v6.x, w1.z, bv.z), 0.f)
              + v7.y * fmaxf(fmaf(v7.x, w1.z, bv.z), 0.f)));
        a3 += ((v0.y * fmaxf(fmaf(v0.x, w1.w, bv.w), 0.f)
              + v1.y * fmaxf(fmaf(v1.x, w1.w, bv.w), 0.f))
             + (v2.y * fmaxf(fmaf(v2.x, w1.w, bv.w), 0.f)
              + v3.y * fmaxf(fmaf(v3.x, w1.w, bv.w), 0.f)))
            + ((v4.y * fmaxf(fmaf(v4.x, w1.w, bv.w), 0.f)
              + v5.y * fmaxf(fmaf(v5.x, w1.w, bv.w), 0.f))
             + (v6.y * fmaxf(fmaf(v6.x, w1.w, bv.w), 0.f)
              + v7.y * fmaxf(fmaf(v7.x, w1.w, bv.w), 0.f)));
    }
    for (; e < e1; ++e) {
        float2 v = td2[csr[e]];
        a0 += v.y * fmaxf(fmaf(v.x, w1.x, bv.x), 0.f);
        a1 += v.y * fmaxf(fmaf(v.x, w1.y, bv.y), 0.f);
        a2 += v.y * fmaxf(fmaf(v.x, w1.z, bv.z), 0.f);
        a3 += v.y * fmaxf(fmaf(v.x, w1.w, bv.w), 0.f);
    }
    out4[(size_t)node * 32 + lane] = make_float4(a0 * dd, a1 * dd, a2 * dd, a3 * dd);
}

// out[d][:] = dis[d] * ( sum_{s in N(d)} hp[s][:] + hp[d][:] ),  F = 128
__global__ void k_agg128(const float4* __restrict__ hp4, const float* __restrict__ dis,
                         const int* __restrict__ row_ptr, const int* __restrict__ csr,
                         float4* __restrict__ out4, int N) {
    int node = blockIdx.x * 8 + (threadIdx.x >> 5);
    int lane = threadIdx.x & 31;
    if (node >= N) return;
    float4 self = hp4[(size_t)node * 32 + lane];
    float a0 = self.x, a1 = self.y, a2 = self.z, a3 = self.w;
    int e0 = row_ptr[node], e1 = row_ptr[node + 1];
    int e = e0;
    for (; e + 8 <= e1; e += 8) {
        int s0 = csr[e],     s1 = csr[e + 1], s2 = csr[e + 2], s3 = csr[e + 3];
        int s4 = csr[e + 4], s5 = csr[e + 5], s6 = csr[e + 6], s7 = csr[e + 7];
        float4 v0 = hp4[(size_t)s0 * 32 + lane];
        float4 v1 = hp4[(size_t)s1 * 32 + lane];
        float4 v2 = hp4[(size_t)s2 * 32 + lane];
        float4 v3 = hp4[(size_t)s3 * 32 + lane];
        float4 v4 = hp4[(size_t)s4 * 32 + lane];
        float4 v5 = hp4[(size_t)s5 * 32 + lane];
        float4 v6 = hp4[(size_t)s6 * 32 + lane];
        float4 v7 = hp4[(size_t)s7 * 32 + lane];
        a0 += ((v0.x + v1.x) + (v2.x + v3.x)) + ((v4.x + v5.x) + (v6.x + v7.x));
        a1 += ((v0.y + v1.y) + (v2.y + v3.y)) + ((v4.y + v5.y) + (v6.y + v7.y));
        a2 += ((v0.z + v1.z) + (v2.z + v3.z)) + ((v4.z + v5.z) + (v6.z + v7.z));
        a3 += ((v0.w + v1.w) + (v2.w + v3.w)) + ((v4.w + v5.w) + (v6.w + v7.w));
    }
    for (; e < e1; ++e) {
        int s = csr[e];
        float4 v = hp4[(size_t)s * 32 + lane];
        a0 += v.x; a1 += v.y; a2 += v.z; a3 += v.w;
    }
    float d = dis[node];
    out4[(size_t)node * 32 + lane] = make_float4(a0 * d, a1 * d, a2 * d, a3 * d);
}

// ---------------------------------------------------------------------------
// W prep: split fp32 W[K][F] into hi/lo bf16, packed in MFMA B-fragment order:
// Wp[k>>3][col][k&7]  (so a lane's 8 contiguous bf16 = one k-group x one col).
__global__ void k_wpack(const float* __restrict__ W, int K, int F,
                        unsigned short* __restrict__ WpH,
                        unsigned short* __restrict__ WpL) {
    int idx = blockIdx.x * 256 + threadIdx.x;
    if (idx >= K * F) return;
    int k = idx / F, col = idx - k * F;
    float v = W[idx];
    unsigned short h = f2bf(v);
    unsigned short l = f2bf(v - bf2f(h));
    int o = ((k >> 3) * F + col) * 8 + (k & 7);
    WpH[o] = h; WpL[o] = l;
}

// MFMA GEMM (split-bf16, 4-term => fp32-level accuracy).
// Block: 64 nodes x 128 cols (jh), 256 thr = 4 waves; wave w = 16-node tile.
// K chunked by 32 = one mfma_f32_16x16x32_bf16 K-step (4 per acc per chunk).
// A: fp32 in global (unchanged producers) -> in-kernel split+pack to LDS.
// W: pre-packed hi/lo bf16 (k_wpack) -> linear b128 copy to LDS.
// Correctness note: A and B fragments use the same (lanegroup,elem)->k map,
// so any HW k-permutation cancels in the dot product; C/D layout is the
// HW-verified col=lane&15, row=(lane>>4)*4+reg.
template<int FOUT, bool SCALE, bool FUSE_MAX>
__global__ __launch_bounds__(256, 3) void k_gemm_mfma(
        const float* __restrict__ A,
        const unsigned short* __restrict__ WpH, const unsigned short* __restrict__ WpL,
        const float* __restrict__ b, const float* __restrict__ dis,
        float* __restrict__ outp, const int* __restrict__ batch,
        unsigned int* __restrict__ gmax, int N) {
    __shared__ __align__(16) unsigned short ApH[4 * 4 * 16 * 8];  // [nt][kg][row][e]
    __shared__ __align__(16) unsigned short ApL[4 * 4 * 16 * 8];
    __shared__ __align__(16) unsigned short WlH[4 * 128 * 8];     // [kg][col][e]
    __shared__ __align__(16) unsigned short WlL[4 * 128 * 8];
    const int tid  = threadIdx.x;
    const int lane = tid & 63;
    const int w    = tid >> 6;        // wave id == node-tile nt
    const int n0   = blockIdx.x * 64;
    const int jh   = blockIdx.y;

    f32x4 acc[8];
#pragma unroll
    for (int ct = 0; ct < 8; ++ct) acc[ct] = (f32x4){0.f, 0.f, 0.f, 0.f};

    for (int kc = 0; kc < 128; kc += 32) {
        // ---- stage W (packed, linear copy) ----
#pragma unroll
        for (int it = 0; it < 2; ++it) {
            int q = tid + it * 256;                    // [0,512) f4 units
            int kg = q >> 7, cq = q & 127;
            int src = ((kc >> 3) + kg) * FOUT + jh * 128 + cq;
            ((f32x4*)WlH)[q] = ((const f32x4*)WpH)[src];
            ((f32x4*)WlL)[q] = ((const f32x4*)WpL)[src];
        }
        // ---- stage A (fp32 -> split bf16, packed) ----
#pragma unroll
        for (int it = 0; it < 2; ++it) {
            int idx = tid + it * 256;                  // [0,512)
            int node = idx >> 3, k4 = idx & 7;
            int gn = n0 + node;
            float4 a = (gn < N)
                ? *reinterpret_cast<const float4*>(A + (size_t)gn * 128 + kc + k4 * 4)
                : make_float4(0.f, 0.f, 0.f, 0.f);
            unsigned short h0 = f2bf(a.x), h1 = f2bf(a.y), h2 = f2bf(a.z), h3 = f2bf(a.w);
            unsigned short l0 = f2bf(a.x - bf2f(h0)), l1 = f2bf(a.y - bf2f(h1));
            unsigned short l2 = f2bf(a.z - bf2f(h2)), l3 = f2bf(a.w - bf2f(h3));
            int kg = k4 >> 1, e0 = (k4 & 1) * 4;
            int base = (((node >> 4) * 4 + kg) * 16 + (node & 15)) * 8 + e0;
            *reinterpret_cast<ushort4*>(&ApH[base]) = make_ushort4(h0, h1, h2, h3);
            *reinterpret_cast<ushort4*>(&ApL[base]) = make_ushort4(l0, l1, l2, l3);
        }
        __syncthreads();

        // ---- MFMA ----
        int aidx = (w * 4 + (lane >> 4)) * 16 + (lane & 15);
        bf16x8 aH = ((const bf16x8*)ApH)[aidx];
        bf16x8 aL = ((const bf16x8*)ApL)[aidx];
#pragma unroll
        for (int ct = 0; ct < 8; ++ct) {
            int bidx = (lane >> 4) * 128 + ct * 16 + (lane & 15);
            bf16x8 bH = ((const bf16x8*)WlH)[bidx];
            bf16x8 bL = ((const bf16x8*)WlL)[bidx];
            acc[ct] = __builtin_amdgcn_mfma_f32_16x16x32_bf16(aL, bL, acc[ct], 0, 0, 0);
            acc[ct] = __builtin_amdgcn_mfma_f32_16x16x32_bf16(aL, bH, acc[ct], 0, 0, 0);
            acc[ct] = __builtin_amdgcn_mfma_f32_16x16x32_bf16(aH, bL, acc[ct], 0, 0, 0);
            acc[ct] = __builtin_amdgcn_mfma_f32_16x16x32_bf16(aH, bH, acc[ct], 0, 0, 0);
        }
        __syncthreads();
    }

    // ---- epilogue: C/D layout col=lane&15, row=(lane>>4)*4+reg ----
    const int cl = lane & 15;
    const int r0 = (lane >> 4) * 4;
    float bb[8];
#pragma unroll
    for (int ct = 0; ct < 8; ++ct) bb[ct] = b[jh * 128 + ct * 16 + cl];

    if (!FUSE_MAX) {
#pragma unroll
        for (int r = 0; r < 4; ++r) {
            int node = n0 + w * 16 + r0 + r;
            if (node < N) {
                float dsc = SCALE ? dis[node] : 1.f;
                float* op = outp + (size_t)node * FOUT + jh * 128 + cl;
#pragma unroll
                for (int ct = 0; ct < 8; ++ct) {
                    float v = fmaxf(acc[ct][r] + bb[ct], 0.f);
                    op[ct * 16] = SCALE ? v * dsc : v;
                }
            }
        }
    } else {
        int nbm[4];
#pragma unroll
        for (int r = 0; r < 4; ++r) {
            int node = n0 + w * 16 + r0 + r;
            nbm[r] = (node < N) ? batch[node] : -1;
        }
        int gfirst = batch[n0];
        int glast  = batch[min(n0 + 63, N - 1)];
        for (int gb = gfirst; gb <= glast; ++gb) {
#pragma unroll
            for (int ct = 0; ct < 8; ++ct) {
                float m = 0.f;
#pragma unroll
                for (int r = 0; r < 4; ++r) {
                    float v = fmaxf(acc[ct][r] + bb[ct], 0.f);
                    if (nbm[r] == gb) m = fmaxf(m, v);
                }
                m = fmaxf(m, __shfl_xor(m, 16));
                m = fmaxf(m, __shfl_xor(m, 32));
                if ((lane >> 4) == 0)
                    atomicMax(&gmax[gb * 256 + jh * 128 + ct * 16 + cl],
                              __float_as_uint(m));
            }
        }
    }
}

// final MLP: out = relu( relu(g@Wf1+bf1) @ Wf2 + bf2 )
__global__ void k_mlp(const float* __restrict__ g, const float* __restrict__ Wf1,
                      const float* __restrict__ bf1, const float* __restrict__ Wf2,
                      const float* __restrict__ bf2, float* __restrict__ out) {
    __shared__ float gr[256];
    __shared__ float g1s[128];
    const int gid = blockIdx.x;
    const int tid = threadIdx.x;
    gr[tid] = g[gid * 256 + tid];
    gr[tid + 128] = g[gid * 256 + 128 + tid];
    __syncthreads();
    float acc = bf1[tid];
    for (int k = 0; k < 256; ++k)
        acc = fmaf(gr[k], Wf1[k * 128 + tid], acc);
    g1s[tid] = fmaxf(acc, 0.f);
    __syncthreads();
    if (tid < 10) {
        float a = bf2[tid];
        for (int k = 0; k < 128; ++k)
            a = fmaf(g1s[k], Wf2[k * 10 + tid], a);
        out[gid * 10 + tid] = fmaxf(a, 0.f);
    }
}

// ---------------------------------------------------------------------------
extern "C" void kernel_launch(void* const* d_in, const int* in_sizes, int n_in,
                              void* d_out, int out_size, void* d_ws, size_t ws_size,
                              hipStream_t stream) {
    const float* x   = (const float*)d_in[0];
    const int*   ei  = (const int*)d_in[1];
    const int*   bat = (const int*)d_in[2];
    const float* W1  = (const float*)d_in[3];
    const float* b1  = (const float*)d_in[4];
    const float* W2  = (const float*)d_in[5];
    const float* b2  = (const float*)d_in[6];
    const float* W3  = (const float*)d_in[7];
    const float* b3  = (const float*)d_in[8];
    const float* Wf1 = (const float*)d_in[9];
    const float* bf1 = (const float*)d_in[10];
    const float* Wf2 = (const float*)d_in[11];
    const float* bf2 = (const float*)d_in[12];
    float* out = (float*)d_out;

    const int N = in_sizes[0];          // 50000
    const int E = in_sizes[1] / 2;      // 800000
    const int* src = ei;
    const int* dst = ei + E;

    char* base = (char*)d_ws;
    size_t off = 0;
    auto carve = [&](size_t bytes) -> char* {
        char* p = base + off;
        off = (off + bytes + 255) & ~(size_t)255;
        return p;
    };
    const int nb = (N + 255) / 256;
    int*    deg     = (int*)   carve((size_t)N * 4);
    int*    fill    = (int*)   carve((size_t)N * 4);
    int*    row_ptr = (int*)   carve((size_t)(N + 1) * 4);
    int*    csr     = (int*)   carve((size_t)E * 4);
    float*  dis     = (float*) carve((size_t)N * 4);
    float*  xp      = (float*) carve((size_t)N * 4);
    float2* td2     = (float2*)carve((size_t)N * 8);
    float*  A2      = (float*) carve((size_t)N * 128 * 4);
    float*  B2      = (float*) carve((size_t)N * 128 * 4);
    float*  A3      = (float*) carve((size_t)N * 128 * 4);
    unsigned int* g = (unsigned int*)carve((size_t)N_GRAPHS * 256 * 4);
    int*    bsum    = (int*)   carve((size_t)nb * 4);
    int*    boff    = (int*)   carve((size_t)nb * 4);
    unsigned short* Wp2H = (unsigned short*)carve((size_t)128 * 128 * 2);
    unsigned short* Wp2L = (unsigned short*)carve((size_t)128 * 128 * 2);
    unsigned short* Wp3H = (unsigned short*)carve((size_t)128 * 256 * 2);
    unsigned short* Wp3L = (unsigned short*)carve((size_t)128 * 256 * 2);
    (void)ws_size; (void)n_in; (void)out_size;

    hipMemsetAsync(deg, 0, (size_t)N * 4, stream);
    hipMemsetAsync(fill, 0, (size_t)N * 4, stream);
    hipMemsetAsync(g, 0, (size_t)N_GRAPHS * 256 * 4, stream);

    int eb = (E + 255) / 256;

    k_deg<<<eb, 256, 0, stream>>>(dst, E, deg);
    k_dis_bsum<<<nb, 256, 0, stream>>>(deg, x, dis, xp, bsum, N);
    k_scan_sums<<<1, 256, 0, stream>>>(bsum, nb, boff);
    k_scan_apply<<<nb, 256, 0, stream>>>(deg, boff, row_ptr, N);
    k_scatter<<<eb, 256, 0, stream>>>(src, dst, E, row_ptr, fill, csr);

    // W split+pack (independent of graph work)
    k_wpack<<<(128 * 128 + 255) / 256, 256, 0, stream>>>(W2, 128, 128, Wp2H, Wp2L);
    k_wpack<<<(128 * 256 + 255) / 256, 256, 0, stream>>>(W3, 128, 256, Wp3H, Wp3L);

    k_agg_scalar<<<nb, 256, 0, stream>>>(xp, dis, row_ptr, csr, td2, N);

    const int gx = (N + 63) / 64;
    const int ab = (N + 7) / 8;

    // layer 1+2: recompute-gather h1 -> A2 (LDS-free), then MFMA GEMM W2 -> B2
    k_h1agg<<<ab, 256, 0, stream>>>(td2, (const float4*)W1, (const float4*)b1,
                                    row_ptr, csr, (float4*)A2, N);
    k_gemm_mfma<128, true, false><<<dim3(gx, 1), 256, 0, stream>>>(
        A2, Wp2H, Wp2L, b2, dis, B2, nullptr, nullptr, N);

    // layer 3: row-gather aggregation, then MFMA GEMM W3 + fused max-pool
    k_agg128<<<ab, 256, 0, stream>>>((const float4*)B2, dis, row_ptr, csr,
                                     (float4*)A3, N);
    k_gemm_mfma<256, false, true><<<dim3(gx, 2), 256, 0, stream>>>(
        A3, Wp3H, Wp3L, b3, nullptr, nullptr, bat, g, N);

    k_mlp<<<N_GRAPHS, 128, 0, stream>>>((const float*)g, Wf1, bf1, Wf2, bf2, out);
}

// Round 12
// 240.511 us; speedup vs baseline: 1.2932x; 1.0400x over previous
//
#include <hip/hip_runtime.h>
#include <hip/hip_bf16.h>

#define N_GRAPHS 64

typedef float f32x4 __attribute__((ext_vector_type(4)));
typedef short bf16x8 __attribute__((ext_vector_type(8)));

__device__ inline unsigned short f2bf(float f) {   // fp32 -> bf16 RNE
    unsigned int u = __float_as_uint(f);
    u = u + 0x7fffu + ((u >> 16) & 1u);
    return (unsigned short)(u >> 16);
}
__device__ inline float bf2f(unsigned short h) {
    return __uint_as_float(((unsigned int)h) << 16);
}

// ---------------------------------------------------------------------------
__global__ void k_deg(const int* __restrict__ dst, int E, int* __restrict__ deg) {
    int i = blockIdx.x * blockDim.x + threadIdx.x;
    if (i < E) atomicAdd(&deg[dst[i]], 1);
}

__global__ void k_dis_bsum(const int* __restrict__ deg, const float* __restrict__ x,
                           float* __restrict__ dis, float* __restrict__ xp,
                           int* __restrict__ bsum, int N) {
    int i = blockIdx.x * 256 + threadIdx.x;
    int dv = (i < N) ? deg[i] : 0;
    if (i < N) {
        float d = rsqrtf((float)(dv + 1));
        dis[i] = d;
        xp[i]  = d * x[i];
    }
    int v = dv;
#pragma unroll
    for (int o = 1; o < 64; o <<= 1) v += __shfl_xor(v, o);
    __shared__ int ws4[4];
    if ((threadIdx.x & 63) == 0) ws4[threadIdx.x >> 6] = v;
    __syncthreads();
    if (threadIdx.x == 0) bsum[blockIdx.x] = ws4[0] + ws4[1] + ws4[2] + ws4[3];
}

__device__ inline int block_scan_inc(int v, int* wsum) {
    int lane = threadIdx.x & 63, w = threadIdx.x >> 6;
    int iv = v;
#pragma unroll
    for (int o = 1; o < 64; o <<= 1) {
        int t = __shfl_up(iv, o);
        if (lane >= o) iv += t;
    }
    if (lane == 63) wsum[w] = iv;
    __syncthreads();
    int add = 0;
    for (int k = 0; k < w; ++k) add += wsum[k];
    return iv + add;
}

__global__ void k_scan_sums(const int* __restrict__ bsum, int nb, int* __restrict__ boff) {
    __shared__ int wsum[4];
    int tid = threadIdx.x;
    int v = (tid < nb) ? bsum[tid] : 0;
    int inc = block_scan_inc(v, wsum);
    if (tid < nb) boff[tid] = inc - v;
}

__global__ void k_scan_apply(const int* __restrict__ deg, const int* __restrict__ boff,
                             int* __restrict__ row_ptr, int N) {
    __shared__ int wsum[4];
    int b = blockIdx.x, i = b * 256 + threadIdx.x;
    int v = (i < N) ? deg[i] : 0;
    int inc = block_scan_inc(v, wsum) + boff[b];
    if (i < N) {
        row_ptr[i] = inc - v;
        if (i == N - 1) row_ptr[N] = inc;
    }
}

__global__ void k_scatter(const int* __restrict__ src, const int* __restrict__ dst, int E,
                          const int* __restrict__ row_ptr, int* __restrict__ fill,
                          int* __restrict__ csr_src) {
    int e = blockIdx.x * blockDim.x + threadIdx.x;
    if (e < E) {
        int d = dst[e];
        int pos = row_ptr[d] + atomicAdd(&fill[d], 1);
        csr_src[pos] = src[e];
    }
}

// td2[d] = ( dis[d] * (sum xp[s] + xp[d]),  dis[d] )
__global__ void k_agg_scalar(const float* __restrict__ xp, const float* __restrict__ dis,
                             const int* __restrict__ row_ptr, const int* __restrict__ csr,
                             float2* __restrict__ td2, int N) {
    int d = blockIdx.x * blockDim.x + threadIdx.x;
    if (d >= N) return;
    float acc = xp[d];
    int e0 = row_ptr[d], e1 = row_ptr[d + 1];
    int e = e0;
    for (; e + 8 <= e1; e += 8) {
        int s0 = csr[e],     s1 = csr[e + 1], s2 = csr[e + 2], s3 = csr[e + 3];
        int s4 = csr[e + 4], s5 = csr[e + 5], s6 = csr[e + 6], s7 = csr[e + 7];
        acc += ((xp[s0] + xp[s1]) + (xp[s2] + xp[s3]))
             + ((xp[s4] + xp[s5]) + (xp[s6] + xp[s7]));
    }
    for (; e < e1; ++e) acc += xp[csr[e]];
    float dd = dis[d];
    td2[d] = make_float2(dd * acc, dd);
}

// ---------------------------------------------------------------------------
// Layer-2 aggregation with rank-1 h1 recompute (LDS-free, high occupancy)
__global__ void k_h1agg(const float2* __restrict__ td2,
                        const float4* __restrict__ W1f4, const float4* __restrict__ b1f4,
                        const int* __restrict__ row_ptr, const int* __restrict__ csr,
                        float4* __restrict__ out4, int N) {
    int node = blockIdx.x * 8 + (threadIdx.x >> 5);
    int lane = threadIdx.x & 31;
    if (node >= N) return;
    const float4 w1 = W1f4[lane];
    const float4 bv = b1f4[lane];
    float2 sv = td2[node];
    float dd = sv.y;
    float a0 = dd * fmaxf(fmaf(sv.x, w1.x, bv.x), 0.f);
    float a1 = dd * fmaxf(fmaf(sv.x, w1.y, bv.y), 0.f);
    float a2 = dd * fmaxf(fmaf(sv.x, w1.z, bv.z), 0.f);
    float a3 = dd * fmaxf(fmaf(sv.x, w1.w, bv.w), 0.f);
    int e0 = row_ptr[node], e1 = row_ptr[node + 1];
    int e = e0;
    for (; e + 8 <= e1; e += 8) {
        int s0 = csr[e],     s1 = csr[e + 1], s2 = csr[e + 2], s3 = csr[e + 3];
        int s4 = csr[e + 4], s5 = csr[e + 5], s6 = csr[e + 6], s7 = csr[e + 7];
        float2 v0 = td2[s0], v1 = td2[s1], v2 = td2[s2], v3 = td2[s3];
        float2 v4 = td2[s4], v5 = td2[s5], v6 = td2[s6], v7 = td2[s7];
        a0 += ((v0.y * fmaxf(fmaf(v0.x, w1.x, bv.x), 0.f)
              + v1.y * fmaxf(fmaf(v1.x, w1.x, bv.x), 0.f))
             + (v2.y * fmaxf(fmaf(v2.x, w1.x, bv.x), 0.f)
              + v3.y * fmaxf(fmaf(v3.x, w1.x, bv.x), 0.f)))
            + ((v4.y * fmaxf(fmaf(v4.x, w1.x, bv.x), 0.f)
              + v5.y * fmaxf(fmaf(v5.x, w1.x, bv.x), 0.f))
             + (v6.y * fmaxf(fmaf(v6.x, w1.x, bv.x), 0.f)
              + v7.y * fmaxf(fmaf(v7.x, w1.x, bv.x), 0.f)));
        a1 += ((v0.y * fmaxf(fmaf(v0.x, w1.y, bv.y), 0.f)
              + v1.y * fmaxf(fmaf(v1.x, w1.y, bv.y), 0.f))
             + (v2.y * fmaxf(fmaf(v2.x, w1.y, bv.y), 0.f)
              + v3.y * fmaxf(fmaf(v3.x, w1.y, bv.y), 0.f)))
            + ((v4.y * fmaxf(fmaf(v4.x, w1.y, bv.y), 0.f)
              + v5.y * fmaxf(fmaf(v5.x, w1.y, bv.y), 0.f))
             + (v6.y * fmaxf(fmaf(v6.x, w1.y, bv.y), 0.f)
              + v7.y * fmaxf(fmaf(v7.x, w1.y, bv.y), 0.f)));
        a2 += ((v0.y * fmaxf(fmaf(v0.x, w1.z, bv.z), 0.f)
              + v1.y * fmaxf(fmaf(v1.x, w1.z, bv.z), 0.f))
             + (v2.y * fmaxf(fmaf(v2.x, w1.z, bv.z), 0.f)
              + v3.y * fmaxf(fmaf(v3.x, w1.z, bv.z), 0.f)))
            + ((v4.y * fmaxf(fmaf(v4.x, w1.z, bv.z), 0.f)
              + v5.y * fmaxf(fmaf(v5.x, w1.z, bv.z), 0.f))
             + (v6.y * fmaxf(fmaf(v6.x, w1.z, bv.z), 0.f)
              + v7.y * fmaxf(fmaf(v7.x, w1.z, bv.z), 0.f)));
        a3 += ((v0.y * fmaxf(fmaf(v0.x, w1.w, bv.w), 0.f)
              + v1.y * fmaxf(fmaf(v1.x, w1.w, bv.w), 0.f))
             + (v2.y * fmaxf(fmaf(v2.x, w1.w, bv.w), 0.f)
              + v3.y * fmaxf(fmaf(v3.x, w1.w, bv.w), 0.f)))
            + ((v4.y * fmaxf(fmaf(v4.x, w1.w, bv.w), 0.f)
              + v5.y * fmaxf(fmaf(v5.x, w1.w, bv.w), 0.f))
             + (v6.y * fmaxf(fmaf(v6.x, w1.w, bv.w), 0.f)
              + v7.y * fmaxf(fmaf(v7.x, w1.w, bv.w), 0.f)));
    }
    for (; e < e1; ++e) {
        float2 v = td2[csr[e]];
        a0 += v.y * fmaxf(fmaf(v.x, w1.x, bv.x), 0.f);
        a1 += v.y * fmaxf(fmaf(v.x, w1.y, bv.y), 0.f);
        a2 += v.y * fmaxf(fmaf(v.x, w1.z, bv.z), 0.f);
        a3 += v.y * fmaxf(fmaf(v.x, w1.w, bv.w), 0.f);
    }
    out4[(size_t)node * 32 + lane] = make_float4(a0 * dd, a1 * dd, a2 * dd, a3 * dd);
}

// Half-row aggregation (F-split): out[d][half] = dis[d]*(sum hp[s][half] + hp[d][half]).
// 16 lanes/node x float4 = 256B rows; two dispatches walk 12.8MB slabs so the
// machine-wide instantaneous working set halves (L2 refetch reduction).
// Nontemporal store keeps the output stream from evicting gather-hot L2 lines.
__global__ void k_agg128h(const float4* __restrict__ hp4, const float* __restrict__ dis,
                          const int* __restrict__ row_ptr, const int* __restrict__ csr,
                          float4* __restrict__ out4, int N, int half) {
    int node = blockIdx.x * 16 + (threadIdx.x >> 4);
    int lane = threadIdx.x & 15;
    if (node >= N) return;
    const int co = half * 16 + lane;           // column offset in float4 units
    float4 self = hp4[(size_t)node * 32 + co];
    float a0 = self.x, a1 = self.y, a2 = self.z, a3 = self.w;
    int e0 = row_ptr[node], e1 = row_ptr[node + 1];
    int e = e0;
    for (; e + 8 <= e1; e += 8) {
        int s0 = csr[e],     s1 = csr[e + 1], s2 = csr[e + 2], s3 = csr[e + 3];
        int s4 = csr[e + 4], s5 = csr[e + 5], s6 = csr[e + 6], s7 = csr[e + 7];
        float4 v0 = hp4[(size_t)s0 * 32 + co];
        float4 v1 = hp4[(size_t)s1 * 32 + co];
        float4 v2 = hp4[(size_t)s2 * 32 + co];
        float4 v3 = hp4[(size_t)s3 * 32 + co];
        float4 v4 = hp4[(size_t)s4 * 32 + co];
        float4 v5 = hp4[(size_t)s5 * 32 + co];
        float4 v6 = hp4[(size_t)s6 * 32 + co];
        float4 v7 = hp4[(size_t)s7 * 32 + co];
        a0 += ((v0.x + v1.x) + (v2.x + v3.x)) + ((v4.x + v5.x) + (v6.x + v7.x));
        a1 += ((v0.y + v1.y) + (v2.y + v3.y)) + ((v4.y + v5.y) + (v6.y + v7.y));
        a2 += ((v0.z + v1.z) + (v2.z + v3.z)) + ((v4.z + v5.z) + (v6.z + v7.z));
        a3 += ((v0.w + v1.w) + (v2.w + v3.w)) + ((v4.w + v5.w) + (v6.w + v7.w));
    }
    for (; e < e1; ++e) {
        int s = csr[e];
        float4 v = hp4[(size_t)s * 32 + co];
        a0 += v.x; a1 += v.y; a2 += v.z; a3 += v.w;
    }
    float d = dis[node];
    f32x4 r = {a0 * d, a1 * d, a2 * d, a3 * d};
    __builtin_nontemporal_store(r, (f32x4*)&out4[(size_t)node * 32 + co]);
}

// ---------------------------------------------------------------------------
// W prep (both weights in one dispatch): split fp32 W[K][F] into hi/lo bf16,
// packed in MFMA B-fragment order Wp[k>>3][col][k&7].
__global__ void k_wpack2(const float* __restrict__ W2, const float* __restrict__ W3,
                         unsigned short* __restrict__ Wp2H, unsigned short* __restrict__ Wp2L,
                         unsigned short* __restrict__ Wp3H, unsigned short* __restrict__ Wp3L) {
    int idx = blockIdx.x * 256 + threadIdx.x;
    const float* W; unsigned short *WpH, *WpL; int F, j;
    if (idx < 128 * 128) { W = W2; WpH = Wp2H; WpL = Wp2L; F = 128; j = idx; }
    else if (idx < 128 * 128 + 128 * 256) {
        W = W3; WpH = Wp3H; WpL = Wp3L; F = 256; j = idx - 128 * 128;
    } else return;
    int k = j / F, col = j - k * F;
    float v = W[j];
    unsigned short h = f2bf(v);
    unsigned short l = f2bf(v - bf2f(h));
    int o = ((k >> 3) * F + col) * 8 + (k & 7);
    WpH[o] = h; WpL[o] = l;
}

// MFMA GEMM (split-bf16, 4-term => fp32-level accuracy).
template<int FOUT, bool SCALE, bool FUSE_MAX>
__global__ __launch_bounds__(256, 3) void k_gemm_mfma(
        const float* __restrict__ A,
        const unsigned short* __restrict__ WpH, const unsigned short* __restrict__ WpL,
        const float* __restrict__ b, const float* __restrict__ dis,
        float* __restrict__ outp, const int* __restrict__ batch,
        unsigned int* __restrict__ gmax, int N) {
    __shared__ __align__(16) unsigned short ApH[4 * 4 * 16 * 8];  // [nt][kg][row][e]
    __shared__ __align__(16) unsigned short ApL[4 * 4 * 16 * 8];
    __shared__ __align__(16) unsigned short WlH[4 * 128 * 8];     // [kg][col][e]
    __shared__ __align__(16) unsigned short WlL[4 * 128 * 8];
    const int tid  = threadIdx.x;
    const int lane = tid & 63;
    const int w    = tid >> 6;        // wave id == node-tile nt
    const int n0   = blockIdx.x * 64;
    const int jh   = blockIdx.y;

    f32x4 acc[8];
#pragma unroll
    for (int ct = 0; ct < 8; ++ct) acc[ct] = (f32x4){0.f, 0.f, 0.f, 0.f};

    for (int kc = 0; kc < 128; kc += 32) {
        // ---- stage W (packed, linear copy) ----
#pragma unroll
        for (int it = 0; it < 2; ++it) {
            int q = tid + it * 256;                    // [0,512) f4 units
            int kg = q >> 7, cq = q & 127;
            int src = ((kc >> 3) + kg) * FOUT + jh * 128 + cq;
            ((f32x4*)WlH)[q] = ((const f32x4*)WpH)[src];
            ((f32x4*)WlL)[q] = ((const f32x4*)WpL)[src];
        }
        // ---- stage A (fp32 -> split bf16, packed) ----
#pragma unroll
        for (int it = 0; it < 2; ++it) {
            int idx = tid + it * 256;                  // [0,512)
            int node = idx >> 3, k4 = idx & 7;
            int gn = n0 + node;
            float4 a = (gn < N)
                ? *reinterpret_cast<const float4*>(A + (size_t)gn * 128 + kc + k4 * 4)
                : make_float4(0.f, 0.f, 0.f, 0.f);
            unsigned short h0 = f2bf(a.x), h1 = f2bf(a.y), h2 = f2bf(a.z), h3 = f2bf(a.w);
            unsigned short l0 = f2bf(a.x - bf2f(h0)), l1 = f2bf(a.y - bf2f(h1));
            unsigned short l2 = f2bf(a.z - bf2f(h2)), l3 = f2bf(a.w - bf2f(h3));
            int kg = k4 >> 1, e0 = (k4 & 1) * 4;
            int base = (((node >> 4) * 4 + kg) * 16 + (node & 15)) * 8 + e0;
            *reinterpret_cast<ushort4*>(&ApH[base]) = make_ushort4(h0, h1, h2, h3);
            *reinterpret_cast<ushort4*>(&ApL[base]) = make_ushort4(l0, l1, l2, l3);
        }
        __syncthreads();

        // ---- MFMA ----
        int aidx = (w * 4 + (lane >> 4)) * 16 + (lane & 15);
        bf16x8 aH = ((const bf16x8*)ApH)[aidx];
        bf16x8 aL = ((const bf16x8*)ApL)[aidx];
#pragma unroll
        for (int ct = 0; ct < 8; ++ct) {
            int bidx = (lane >> 4) * 128 + ct * 16 + (lane & 15);
            bf16x8 bH = ((const bf16x8*)WlH)[bidx];
            bf16x8 bL = ((const bf16x8*)WlL)[bidx];
            acc[ct] = __builtin_amdgcn_mfma_f32_16x16x32_bf16(aL, bL, acc[ct], 0, 0, 0);
            acc[ct] = __builtin_amdgcn_mfma_f32_16x16x32_bf16(aL, bH, acc[ct], 0, 0, 0);
            acc[ct] = __builtin_amdgcn_mfma_f32_16x16x32_bf16(aH, bL, acc[ct], 0, 0, 0);
            acc[ct] = __builtin_amdgcn_mfma_f32_16x16x32_bf16(aH, bH, acc[ct], 0, 0, 0);
        }
        __syncthreads();
    }

    // ---- epilogue: C/D layout col=lane&15, row=(lane>>4)*4+reg ----
    const int cl = lane & 15;
    const int r0 = (lane >> 4) * 4;
    float bb[8];
#pragma unroll
    for (int ct = 0; ct < 8; ++ct) bb[ct] = b[jh * 128 + ct * 16 + cl];

    if (!FUSE_MAX) {
#pragma unroll
        for (int r = 0; r < 4; ++r) {
            int node = n0 + w * 16 + r0 + r;
            if (node < N) {
                float dsc = SCALE ? dis[node] : 1.f;
                float* op = outp + (size_t)node * FOUT + jh * 128 + cl;
#pragma unroll
                for (int ct = 0; ct < 8; ++ct) {
                    float v = fmaxf(acc[ct][r] + bb[ct], 0.f);
                    op[ct * 16] = SCALE ? v * dsc : v;
                }
            }
        }
    } else {
        int nbm[4];
#pragma unroll
        for (int r = 0; r < 4; ++r) {
            int node = n0 + w * 16 + r0 + r;
            nbm[r] = (node < N) ? batch[node] : -1;
        }
        int gfirst = batch[n0];
        int glast  = batch[min(n0 + 63, N - 1)];
        for (int gb = gfirst; gb <= glast; ++gb) {
#pragma unroll
            for (int ct = 0; ct < 8; ++ct) {
                float m = 0.f;
#pragma unroll
                for (int r = 0; r < 4; ++r) {
                    float v = fmaxf(acc[ct][r] + bb[ct], 0.f);
                    if (nbm[r] == gb) m = fmaxf(m, v);
                }
                m = fmaxf(m, __shfl_xor(m, 16));
                m = fmaxf(m, __shfl_xor(m, 32));
                if ((lane >> 4) == 0)
                    atomicMax(&gmax[gb * 256 + jh * 128 + ct * 16 + cl],
                              __float_as_uint(m));
            }
        }
    }
}

// final MLP: out = relu( relu(g@Wf1+bf1) @ Wf2 + bf2 )
__global__ void k_mlp(const float* __restrict__ g, const float* __restrict__ Wf1,
                      const float* __restrict__ bf1, const float* __restrict__ Wf2,
                      const float* __restrict__ bf2, float* __restrict__ out) {
    __shared__ float gr[256];
    __shared__ float g1s[128];
    const int gid = blockIdx.x;
    const int tid = threadIdx.x;
    gr[tid] = g[gid * 256 + tid];
    gr[tid + 128] = g[gid * 256 + 128 + tid];
    __syncthreads();
    float acc = bf1[tid];
    for (int k = 0; k < 256; ++k)
        acc = fmaf(gr[k], Wf1[k * 128 + tid], acc);
    g1s[tid] = fmaxf(acc, 0.f);
    __syncthreads();
    if (tid < 10) {
        float a = bf2[tid];
        for (int k = 0; k < 128; ++k)
            a = fmaf(g1s[k], Wf2[k * 10 + tid], a);
        out[gid * 10 + tid] = fmaxf(a, 0.f);
    }
}

// ---------------------------------------------------------------------------
extern "C" void kernel_launch(void* const* d_in, const int* in_sizes, int n_in,
                              void* d_out, int out_size, void* d_ws, size_t ws_size,
                              hipStream_t stream) {
    const float* x   = (const float*)d_in[0];
    const int*   ei  = (const int*)d_in[1];
    const int*   bat = (const int*)d_in[2];
    const float* W1  = (const float*)d_in[3];
    const float* b1  = (const float*)d_in[4];
    const float* W2  = (const float*)d_in[5];
    const float* b2  = (const float*)d_in[6];
    const float* W3  = (const float*)d_in[7];
    const float* b3  = (const float*)d_in[8];
    const float* Wf1 = (const float*)d_in[9];
    const float* bf1 = (const float*)d_in[10];
    const float* Wf2 = (const float*)d_in[11];
    const float* bf2 = (const float*)d_in[12];
    float* out = (float*)d_out;

    const int N = in_sizes[0];          // 50000
    const int E = in_sizes[1] / 2;      // 800000
    const int* src = ei;
    const int* dst = ei + E;

    char* base = (char*)d_ws;
    size_t off = 0;
    auto carve = [&](size_t bytes) -> char* {
        char* p = base + off;
        off = (off + bytes + 255) & ~(size_t)255;
        return p;
    };
    const int nb = (N + 255) / 256;
    int*    deg     = (int*)   carve((size_t)N * 4);
    int*    fill    = (int*)   carve((size_t)N * 4);
    int*    row_ptr = (int*)   carve((size_t)(N + 1) * 4);
    int*    csr     = (int*)   carve((size_t)E * 4);
    float*  dis     = (float*) carve((size_t)N * 4);
    float*  xp      = (float*) carve((size_t)N * 4);
    float2* td2     = (float2*)carve((size_t)N * 8);
    float*  A2      = (float*) carve((size_t)N * 128 * 4);
    float*  B2      = (float*) carve((size_t)N * 128 * 4);
    float*  A3      = (float*) carve((size_t)N * 128 * 4);
    unsigned int* g = (unsigned int*)carve((size_t)N_GRAPHS * 256 * 4);
    int*    bsum    = (int*)   carve((size_t)nb * 4);
    int*    boff    = (int*)   carve((size_t)nb * 4);
    unsigned short* Wp2H = (unsigned short*)carve((size_t)128 * 128 * 2);
    unsigned short* Wp2L = (unsigned short*)carve((size_t)128 * 128 * 2);
    unsigned short* Wp3H = (unsigned short*)carve((size_t)128 * 256 * 2);
    unsigned short* Wp3L = (unsigned short*)carve((size_t)128 * 256 * 2);
    (void)ws_size; (void)n_in; (void)out_size;

    // deg+fill are adjacent in the carve order: one memset covers both
    hipMemsetAsync(deg, 0, (size_t)((char*)row_ptr - (char*)deg), stream);
    hipMemsetAsync(g, 0, (size_t)N_GRAPHS * 256 * 4, stream);

    int eb = (E + 255) / 256;

    k_deg<<<eb, 256, 0, stream>>>(dst, E, deg);
    k_dis_bsum<<<nb, 256, 0, stream>>>(deg, x, dis, xp, bsum, N);
    k_scan_sums<<<1, 256, 0, stream>>>(bsum, nb, boff);
    k_scan_apply<<<nb, 256, 0, stream>>>(deg, boff, row_ptr, N);
    k_scatter<<<eb, 256, 0, stream>>>(src, dst, E, row_ptr, fill, csr);

    // W split+pack (both weights, one dispatch)
    k_wpack2<<<(128 * 128 + 128 * 256 + 255) / 256, 256, 0, stream>>>(
        W2, W3, Wp2H, Wp2L, Wp3H, Wp3L);

    k_agg_scalar<<<nb, 256, 0, stream>>>(xp, dis, row_ptr, csr, td2, N);

    const int gx = (N + 63) / 64;
    const int ab = (N + 7) / 8;
    const int ab16 = (N + 15) / 16;

    // layer 1+2: recompute-gather h1 -> A2 (LDS-free), then MFMA GEMM W2 -> B2
    k_h1agg<<<ab, 256, 0, stream>>>(td2, (const float4*)W1, (const float4*)b1,
                                    row_ptr, csr, (float4*)A2, N);
    k_gemm_mfma<128, true, false><<<dim3(gx, 1), 256, 0, stream>>>(
        A2, Wp2H, Wp2L, b2, dis, B2, nullptr, nullptr, N);

    // layer 3: F-split row-gather aggregation (two 12.8MB slabs), then
    // MFMA GEMM W3 + fused max-pool
    k_agg128h<<<ab16, 256, 0, stream>>>((const float4*)B2, dis, row_ptr, csr,
                                        (float4*)A3, N, 0);
    k_agg128h<<<ab16, 256, 0, stream>>>((const float4*)B2, dis, row_ptr, csr,
                                        (float4*)A3, N, 1);
    k_gemm_mfma<256, false, true><<<dim3(gx, 2), 256, 0, stream>>>(
        A3, Wp3H, Wp3L, b3, nullptr, nullptr, bat, g, N);

    k_mlp<<<N_GRAPHS, 128, 0, stream>>>((const float*)g, Wf1, bf1, Wf2, bf2, out);
}